// Round 11
// baseline (209.079 us; speedup 1.0000x reference)
//
#include <hip/hip_runtime.h>
#include <hip/hip_bf16.h>
#include <math.h>

#define GPB     24   // graphs per block (3 per wave, exactly balanced)
#define THREADS 512  // 8 waves
#define NWAVES  8
#define BATCH   8    // float4 loads in flight per wave (8 KB)

typedef float fx4 __attribute__((ext_vector_type(4)));

#define POOL_CONSUME(vv)                                        \
    do {                                                        \
        sx += (vv).x; sy += (vv).y; sz += (vv).z; sw += (vv).w; \
        mx = fmaxf(mx, (vv).x); my = fmaxf(my, (vv).y);         \
        mz = fmaxf(mz, (vv).z); mw = fmaxf(mw, (vv).w);         \
    } while (0)

__global__ __launch_bounds__(THREADS, 4) void fused_pool_mlp_kernel(
    const float* __restrict__ feats, const int* __restrict__ gsize,
    const float* __restrict__ W0, const float* __restrict__ b0,
    const float* __restrict__ W1, const float* __restrict__ b1,
    const float* __restrict__ W2, const float* __restrict__ b2,
    float* __restrict__ out, int G)
{
    __shared__ __align__(16) float4 X4[GPB * 64];   // pooled [GPB][256]
    __shared__ __align__(16) float  H0[GPB * 256];
    __shared__ __align__(16) float  H1[GPB * 128];
    __shared__ int soff[GPB], ssize[GPB];
    __shared__ int red[NWAVES];

    int t    = threadIdx.x;
    int lane = t & 63;
    int wave = t >> 6;
    int g0   = blockIdx.x * GPB;

    // ---- per-block base offset: sum gsize[0:g0) cooperatively, int4-vectorized
    // (g0 is a multiple of 24, so g0/4 int4 elements exactly cover it)
    int partial = 0;
    {
        const int4* gs4 = (const int4*)gsize;
        int n4 = g0 >> 2;
        for (int i = t; i < n4; i += THREADS) {
            int4 v = gs4[i];
            partial += v.x + v.y + v.z + v.w;
        }
    }
    #pragma unroll
    for (int d = 32; d > 0; d >>= 1) partial += __shfl_xor(partial, d);
    if (lane == 0) red[wave] = partial;
    __syncthreads();
    if (t == 0) {
        int base = 0;
        #pragma unroll
        for (int w = 0; w < NWAVES; ++w) base += red[w];
        #pragma unroll
        for (int q = 0; q < GPB; ++q) {
            int g = g0 + q;
            int n = (g < G) ? gsize[g] : 0;
            soff[q] = base; ssize[q] = n; base += n;
        }
    }
    __syncthreads();

    // ---- pooling: wave w pools graphs {w, w+8, w+16} (3 each, balanced);
    // mean lanes 0-31, max lanes 32-63
    const float NEG = -3.402823466e38f;
    #pragma unroll 1
    for (int gi = wave; gi < GPB; gi += NWAVES) {
        int n = ssize[gi];
        float4 outv = make_float4(0.f, 0.f, 0.f, 0.f);
        if (n > 0) {
            const fx4* p = (const fx4*)feats + (size_t)soff[gi] * 32;
            float sx = 0.f, sy = 0.f, sz = 0.f, sw = 0.f;
            float mx = NEG, my = NEG, mz = NEG, mw = NEG;
            int npairs = n >> 1;
            int i = 0;
            for (; i + BATCH <= npairs; i += BATCH) {   // BATCH float4 nt loads in flight
                fx4 v[BATCH];
                #pragma unroll
                for (int u = 0; u < BATCH; ++u)
                    v[u] = __builtin_nontemporal_load(p + (size_t)(i + u) * 64 + lane);
                #pragma unroll
                for (int u = 0; u < BATCH; ++u) POOL_CONSUME(v[u]);
            }
            for (; i < npairs; ++i) {
                fx4 v = __builtin_nontemporal_load(p + (size_t)i * 64 + lane);
                POOL_CONSUME(v);
            }
            if ((n & 1) && lane < 32) {           // odd last row, lanes 0-31
                fx4 v = __builtin_nontemporal_load(p + (size_t)(n - 1) * 32 + lane);
                POOL_CONSUME(v);
            }
            // combine the two half-wave accumulators (opposite-parity rows)
            sx += __shfl_xor(sx, 32); sy += __shfl_xor(sy, 32);
            sz += __shfl_xor(sz, 32); sw += __shfl_xor(sw, 32);
            mx = fmaxf(mx, __shfl_xor(mx, 32)); my = fmaxf(my, __shfl_xor(my, 32));
            mz = fmaxf(mz, __shfl_xor(mz, 32)); mw = fmaxf(mw, __shfl_xor(mw, 32));
            if (lane < 32) {
                float invn = 1.0f / (float)n;
                outv = make_float4(sx * invn, sy * invn, sz * invn, sw * invn);
            } else {
                outv = make_float4(mx, my, mz, mw);
            }
        }
        X4[gi * 64 + lane] = outv;   // lanes 0-31: mean cols, 32-63: max cols
    }
    __syncthreads();

    // ---- layer 0: H0[GPB][256] = relu(X @ W0 + b0), W0 [256][256] row-major
    // 512 threads: j = t&255, gq = t>>8 selects graphs gq*12 .. gq*12+11
    {
        int j  = t & 255;
        int gq = t >> 8;                           // 0/1, wave-uniform
        float acc[12];
        float bb = b0[j];
        #pragma unroll
        for (int q = 0; q < 12; ++q) acc[q] = bb;
        for (int k4 = 0; k4 < 64; ++k4) {
            const float* Wk = W0 + (size_t)k4 * 1024;
            float w0v = Wk[j], w1v = Wk[256 + j], w2v = Wk[512 + j], w3v = Wk[768 + j];
            #pragma unroll
            for (int q = 0; q < 12; ++q) {
                float4 x = X4[(gq * 12 + q) * 64 + k4];   // LDS broadcast
                acc[q] = fmaf(x.x, w0v, acc[q]);
                acc[q] = fmaf(x.y, w1v, acc[q]);
                acc[q] = fmaf(x.z, w2v, acc[q]);
                acc[q] = fmaf(x.w, w3v, acc[q]);
            }
        }
        #pragma unroll
        for (int q = 0; q < 12; ++q)
            H0[(gq * 12 + q) * 256 + j] = fmaxf(acc[q], 0.f);
    }
    __syncthreads();

    // ---- layer 1: H1[GPB][128] = relu(H0 @ W1 + b1), W1 [256][128]
    // j = t&127, gq = t>>7 selects graphs gq*6 .. gq*6+5
    {
        int j  = t & 127;
        int gq = t >> 7;                           // 0..3, wave-uniform
        float acc[6];
        float bb = b1[j];
        #pragma unroll
        for (int q = 0; q < 6; ++q) acc[q] = bb;
        const float4* H04 = (const float4*)H0;
        for (int k4 = 0; k4 < 64; ++k4) {
            const float* Wk = W1 + (size_t)k4 * 512;
            float w0v = Wk[j],       w1v = Wk[128 + j];
            float w2v = Wk[256 + j], w3v = Wk[384 + j];
            #pragma unroll
            for (int q = 0; q < 6; ++q) {
                float4 x = H04[(gq * 6 + q) * 64 + k4];   // LDS broadcast
                acc[q] = fmaf(x.x, w0v, acc[q]);
                acc[q] = fmaf(x.y, w1v, acc[q]);
                acc[q] = fmaf(x.z, w2v, acc[q]);
                acc[q] = fmaf(x.w, w3v, acc[q]);
            }
        }
        #pragma unroll
        for (int q = 0; q < 6; ++q)
            H1[(gq * 6 + q) * 128 + j] = fmaxf(acc[q], 0.f);
    }
    __syncthreads();

    // ---- layer 2: out[g] = sigmoid(H1[g] . W2 + b2); 32 lanes per graph
    // pass 0: graphs 0..15, pass 1: graphs 16..23
    {
        int gi0 = t >> 5;    // 0..15
        int sub = t & 31;
        #pragma unroll
        for (int pass = 0; pass < 2; ++pass) {
            int gi = gi0 + pass * 16;
            if (gi < GPB) {
                float acc = 0.f;
                #pragma unroll
                for (int kk = 0; kk < 4; ++kk) {
                    int k = sub + kk * 32;
                    acc = fmaf(H1[gi * 128 + k], W2[k], acc);
                }
                acc += __shfl_xor(acc, 16);
                acc += __shfl_xor(acc, 8);
                acc += __shfl_xor(acc, 4);
                acc += __shfl_xor(acc, 2);
                acc += __shfl_xor(acc, 1);
                int g = g0 + gi;
                if (sub == 0 && g < G)
                    out[g] = 1.0f / (1.0f + expf(-(acc + b2[0])));
            }
        }
    }
}

extern "C" void kernel_launch(void* const* d_in, const int* in_sizes, int n_in,
                              void* d_out, int out_size, void* d_ws, size_t ws_size,
                              hipStream_t stream) {
    const float* feats = (const float*)d_in[0];
    const int*   gsize = (const int*)d_in[1];
    const float* W0 = (const float*)d_in[2];
    const float* b0 = (const float*)d_in[3];
    const float* W1 = (const float*)d_in[4];
    const float* b1 = (const float*)d_in[5];
    const float* W2 = (const float*)d_in[6];
    const float* b2 = (const float*)d_in[7];
    float* out = (float*)d_out;

    int G = in_sizes[1];
    int blocks = (G + GPB - 1) / GPB;
    fused_pool_mlp_kernel<<<blocks, THREADS, 0, stream>>>(
        feats, gsize, W0, b0, W1, b1, W2, b2, out, G);
}

// Round 12
// 191.168 us; speedup vs baseline: 1.0937x; 1.0937x over previous
//
#include <hip/hip_runtime.h>
#include <hip/hip_bf16.h>
#include <math.h>

#define GPB     20   // graphs per block
#define THREADS 512  // 8 waves
#define NWAVES  8
#define BATCH   8    // float4 loads in flight per wave (8 KB)

typedef float fx4 __attribute__((ext_vector_type(4)));

#define POOL_CONSUME(vv)                                        \
    do {                                                        \
        sx += (vv).x; sy += (vv).y; sz += (vv).z; sw += (vv).w; \
        mx = fmaxf(mx, (vv).x); my = fmaxf(my, (vv).y);         \
        mz = fmaxf(mz, (vv).z); mw = fmaxf(mw, (vv).w);         \
    } while (0)

__global__ __launch_bounds__(THREADS, 4) void fused_pool_mlp_kernel(
    const float* __restrict__ feats, const int* __restrict__ gsize,
    const float* __restrict__ W0, const float* __restrict__ b0,
    const float* __restrict__ W1, const float* __restrict__ b1,
    const float* __restrict__ W2, const float* __restrict__ b2,
    float* __restrict__ out, int G)
{
    __shared__ __align__(16) float4 X4[GPB * 64];   // pooled [GPB][256]
    __shared__ __align__(16) float  H0[GPB * 256];
    __shared__ __align__(16) float  H1[GPB * 128];
    __shared__ int soff[GPB], ssize[GPB];
    __shared__ int red[NWAVES];

    int t    = threadIdx.x;
    int lane = t & 63;
    int wave = t >> 6;
    int g0   = blockIdx.x * GPB;

    // ---- per-block base offset: sum gsize[0:g0) cooperatively, int4-vectorized
    int partial = 0;
    {
        const int4* gs4 = (const int4*)gsize;
        int n4 = g0 >> 2;
        for (int i = t; i < n4; i += THREADS) {
            int4 v = gs4[i];
            partial += v.x + v.y + v.z + v.w;
        }
    }
    #pragma unroll
    for (int d = 32; d > 0; d >>= 1) partial += __shfl_xor(partial, d);
    if (lane == 0) red[wave] = partial;
    __syncthreads();
    if (t == 0) {
        int base = 0;
        #pragma unroll
        for (int w = 0; w < NWAVES; ++w) base += red[w];
        for (int q = 0; q < GPB; ++q) {
            int g = g0 + q;
            int n = (g < G) ? gsize[g] : 0;
            soff[q] = base; ssize[q] = n; base += n;
        }
    }
    __syncthreads();

    // ---- pooling: wave w pools graphs {w, w+8, w+16<GPB}; mean lanes 0-31, max 32-63
    const float NEG = -3.402823466e38f;
    #pragma unroll 1
    for (int gi = wave; gi < GPB; gi += NWAVES) {
        int n = ssize[gi];
        float4 outv = make_float4(0.f, 0.f, 0.f, 0.f);
        if (n > 0) {
            const fx4* p = (const fx4*)feats + (size_t)soff[gi] * 32;
            float sx = 0.f, sy = 0.f, sz = 0.f, sw = 0.f;
            float mx = NEG, my = NEG, mz = NEG, mw = NEG;
            int npairs = n >> 1;
            int i = 0;
            for (; i + BATCH <= npairs; i += BATCH) {   // BATCH float4 nt loads in flight
                fx4 v[BATCH];
                #pragma unroll
                for (int u = 0; u < BATCH; ++u)
                    v[u] = __builtin_nontemporal_load(p + (size_t)(i + u) * 64 + lane);
                #pragma unroll
                for (int u = 0; u < BATCH; ++u) POOL_CONSUME(v[u]);
            }
            for (; i < npairs; ++i) {
                fx4 v = __builtin_nontemporal_load(p + (size_t)i * 64 + lane);
                POOL_CONSUME(v);
            }
            if ((n & 1) && lane < 32) {           // odd last row, lanes 0-31
                fx4 v = __builtin_nontemporal_load(p + (size_t)(n - 1) * 32 + lane);
                POOL_CONSUME(v);
            }
            // combine the two half-wave accumulators (opposite-parity rows)
            sx += __shfl_xor(sx, 32); sy += __shfl_xor(sy, 32);
            sz += __shfl_xor(sz, 32); sw += __shfl_xor(sw, 32);
            mx = fmaxf(mx, __shfl_xor(mx, 32)); my = fmaxf(my, __shfl_xor(my, 32));
            mz = fmaxf(mz, __shfl_xor(mz, 32)); mw = fmaxf(mw, __shfl_xor(mw, 32));
            if (lane < 32) {
                float invn = 1.0f / (float)n;
                outv = make_float4(sx * invn, sy * invn, sz * invn, sw * invn);
            } else {
                outv = make_float4(mx, my, mz, mw);
            }
        }
        X4[gi * 64 + lane] = outv;   // lanes 0-31: mean cols, 32-63: max cols
    }
    __syncthreads();

    // ---- layer 0: H0[GPB][256] = relu(X @ W0 + b0), W0 [256][256] row-major
    // 512 threads: j = t&255, gq = t>>8 selects graphs gq*10 .. gq*10+9
    {
        int j  = t & 255;
        int gq = t >> 8;                           // 0/1, wave-uniform
        float acc[10];
        float bb = b0[j];
        #pragma unroll
        for (int q = 0; q < 10; ++q) acc[q] = bb;
        for (int k4 = 0; k4 < 64; ++k4) {
            const float* Wk = W0 + (size_t)k4 * 1024;
            float w0v = Wk[j], w1v = Wk[256 + j], w2v = Wk[512 + j], w3v = Wk[768 + j];
            #pragma unroll
            for (int q = 0; q < 10; ++q) {
                float4 x = X4[(gq * 10 + q) * 64 + k4];   // LDS broadcast
                acc[q] = fmaf(x.x, w0v, acc[q]);
                acc[q] = fmaf(x.y, w1v, acc[q]);
                acc[q] = fmaf(x.z, w2v, acc[q]);
                acc[q] = fmaf(x.w, w3v, acc[q]);
            }
        }
        #pragma unroll
        for (int q = 0; q < 10; ++q)
            H0[(gq * 10 + q) * 256 + j] = fmaxf(acc[q], 0.f);
    }
    __syncthreads();

    // ---- layer 1: H1[GPB][128] = relu(H0 @ W1 + b1), W1 [256][128]
    // j = t&127, gq = t>>7 selects graphs gq*5 .. gq*5+4
    {
        int j  = t & 127;
        int gq = t >> 7;                           // 0..3, wave-uniform
        float acc[5];
        float bb = b1[j];
        #pragma unroll
        for (int q = 0; q < 5; ++q) acc[q] = bb;
        const float4* H04 = (const float4*)H0;
        for (int k4 = 0; k4 < 64; ++k4) {
            const float* Wk = W1 + (size_t)k4 * 512;
            float w0v = Wk[j],       w1v = Wk[128 + j];
            float w2v = Wk[256 + j], w3v = Wk[384 + j];
            #pragma unroll
            for (int q = 0; q < 5; ++q) {
                float4 x = H04[(gq * 5 + q) * 64 + k4];   // LDS broadcast
                acc[q] = fmaf(x.x, w0v, acc[q]);
                acc[q] = fmaf(x.y, w1v, acc[q]);
                acc[q] = fmaf(x.z, w2v, acc[q]);
                acc[q] = fmaf(x.w, w3v, acc[q]);
            }
        }
        #pragma unroll
        for (int q = 0; q < 5; ++q)
            H1[(gq * 5 + q) * 128 + j] = fmaxf(acc[q], 0.f);
    }
    __syncthreads();

    // ---- layer 2: out[g] = sigmoid(H1[g] . W2 + b2); 16 lanes per graph
    {
        int gi  = t >> 4;    // 0..31
        int sub = t & 15;
        if (gi < GPB) {
            float acc = 0.f;
            #pragma unroll
            for (int kk = 0; kk < 8; ++kk) {
                int k = sub + kk * 16;
                acc = fmaf(H1[gi * 128 + k], W2[k], acc);
            }
            acc += __shfl_xor(acc, 8);
            acc += __shfl_xor(acc, 4);
            acc += __shfl_xor(acc, 2);
            acc += __shfl_xor(acc, 1);
            int g = g0 + gi;
            if (sub == 0 && g < G)
                out[g] = 1.0f / (1.0f + expf(-(acc + b2[0])));
        }
    }
}

extern "C" void kernel_launch(void* const* d_in, const int* in_sizes, int n_in,
                              void* d_out, int out_size, void* d_ws, size_t ws_size,
                              hipStream_t stream) {
    const float* feats = (const float*)d_in[0];
    const int*   gsize = (const int*)d_in[1];
    const float* W0 = (const float*)d_in[2];
    const float* b0 = (const float*)d_in[3];
    const float* W1 = (const float*)d_in[4];
    const float* b1 = (const float*)d_in[5];
    const float* W2 = (const float*)d_in[6];
    const float* b2 = (const float*)d_in[7];
    float* out = (float*)d_out;

    int G = in_sizes[1];
    int blocks = (G + GPB - 1) / GPB;
    fused_pool_mlp_kernel<<<blocks, THREADS, 0, stream>>>(
        feats, gsize, W0, b0, W1, b1, W2, b2, out, G);
}